// Round 1
// baseline (140.800 us; speedup 1.0000x reference)
//
#include <hip/hip_runtime.h>
#include <stdint.h>

// CropConv, fully fused single-kernel implicit GEMM (bf16 MFMA, fp32 accum).
//   M=64 (oc), K=576 (ic*3*3), N=262144 (b*h*w)
// Per block (2 output rows x 128 w x 64 oc):
//   - stage weights fp32->bf16 into LDS [kk][ch][i][lane] (lane-contiguous
//     A-fragments -> conflict-free ds_read_b128, no global gather, no L1 thrash)
//   - stage input fp32 NCHW -> bf16 [r:4][c:128][slot:8] LDS tile with the
//     XOR-rotate swizzle j' = (j + c) & 7 (same swizzle as verified kernel)
//   - 18 straight-line K-steps of 4x4 16x16x32 MFMA tiles (no barriers in loop)
// No workspace used at all (removes the ws-size fallback gamble).
// LDS 136 KiB -> 1 block/CU, 4 waves, launch_bounds(256,1) -> 512 VGPR budget.

#define B_ 16
#define C_ 64
#define H_ 128
#define W_ 128

#define WLDS_U4 4608   // 9*2*4*64 uint4 = 72 KiB weights
#define XLDS_U4 4096   // 4*128*8 uint4 = 64 KiB input tile

typedef float f32x4 __attribute__((ext_vector_type(4)));
typedef short bf16x8 __attribute__((ext_vector_type(8)));

__device__ inline unsigned short f2bf(float f) {
    union { float f; uint32_t u; } v; v.f = f;
    uint32_t u = v.u + 0x7FFF + ((v.u >> 16) & 1);   // RNE
    return (unsigned short)(u >> 16);
}

__global__ __launch_bounds__(256, 1) void conv_fused(
    const float* __restrict__ x,     // [16][64][128][128] fp32
    const float* __restrict__ wgt,   // [64][64][3][3] fp32
    float* __restrict__ out)         // [16][64][128][128] fp32
{
    __shared__ uint4 lds[WLDS_U4 + XLDS_U4];          // 136 KiB
    uint16_t* lds16 = (uint16_t*)lds;

    const int t    = threadIdx.x;
    const int lane = t & 63;
    const int wv   = t >> 6;
    const int n    = lane & 15;
    const int q    = lane >> 4;

    // XCD-contiguous remap: hw-consecutive blocks round-robin XCDs; map so each
    // XCD owns 128 consecutive logical blocks -> neighbor h-tiles share L2 rows.
    const int d    = blockIdx.x;                       // 0..1023 (= 8 * 128)
    const int orig = (d & 7) * 128 + (d >> 3);
    const int b    = orig >> 6;
    const int h0   = (orig & 63) * 2;

    // ---- stage weights: fp32 [oc][ic][kk] -> LDS bf16 [kk][ch][i][lane] ----
    // assignment a = t + 256p: oc = a>>3, ic-octet = a&7 (72 contiguous floats)
    #pragma unroll
    for (int p = 0; p < 2; ++p) {
        const int a_  = t + 256 * p;                   // 0..511
        const int oc  = a_ >> 3;
        const int oct = a_ & 7;
        const float* src = wgt + (size_t)oc * 576 + (size_t)oct * 72;
        f32x4 w4[18];
        #pragma unroll
        for (int j = 0; j < 18; ++j) w4[j] = ((const f32x4*)src)[j];
        const int ch = oct >> 2, qq = oct & 3;
        const int ii = oc >> 4,  nn = oc & 15;
        #pragma unroll
        for (int kk = 0; kk < 9; ++kk) {
            // element e of the uint4 = ic (oct*8+e) at kernel-pos kk
            #define WELEM(e) ((uint32_t)f2bf(w4[((e)*9 + kk) >> 2][((e)*9 + kk) & 3]))
            uint4 val;
            val.x = WELEM(0) | (WELEM(1) << 16);
            val.y = WELEM(2) | (WELEM(3) << 16);
            val.z = WELEM(4) | (WELEM(5) << 16);
            val.w = WELEM(6) | (WELEM(7) << 16);
            #undef WELEM
            lds[((kk * 2 + ch) * 4 + ii) * 64 + qq * 16 + nn] = val;
        }
    }

    // ---- stage input: x[b][ic][h][w] fp32 -> swizzled bf16 tile ----
    // thread: ic = t>>2 (one plane), w-quarter = t&3 (32 w). Coalesced 16B loads.
    {
        const int ic    = t >> 2;
        const int w0    = (t & 3) * 32;
        const int jslot = ic >> 3;                     // original uint4-in-col
        const int esub  = ic & 7;
        #pragma unroll
        for (int r = 0; r < 4; ++r) {
            const int h = h0 - 1 + r;                  // -1..128
            if (h < 0 || h >= H_) {                    // zero halo row (uniform)
                uint4 z; z.x = z.y = z.z = z.w = 0;
                #pragma unroll
                for (int k = 0; k < 4; ++k)
                    lds[WLDS_U4 + r * 1024 + k * 256 + t] = z;
            } else {
                const float* src =
                    x + (((size_t)(b * C_ + ic)) * H_ + h) * W_ + w0;
                f32x4 v4[8];
                #pragma unroll
                for (int j = 0; j < 8; ++j) v4[j] = ((const f32x4*)src)[j];
                #pragma unroll
                for (int k = 0; k < 32; ++k) {
                    const int c    = w0 + k;
                    const int slot = (jslot + c) & 7;  // XOR-rotate swizzle
                    lds16[WLDS_U4 * 8 + ((r * 128 + c) * 8 + slot) * 8 + esub] =
                        f2bf(v4[k >> 2][k & 3]);
                }
            }
        }
    }
    __syncthreads();

    // ---- K-loop: 18 steps (3 kh x 3 kw x 2 ch), 4x4 MFMA tiles per wave ----
    f32x4 acc[4][4];
    #pragma unroll
    for (int i = 0; i < 4; ++i)
        #pragma unroll
        for (int tt = 0; tt < 4; ++tt)
            acc[i][tt] = (f32x4){0.f, 0.f, 0.f, 0.f};

    const int wb = (wv & 1) * 64;
    const uint4* Wl = lds;                 // weight region
    const uint4* Xl = lds + WLDS_U4;       // input region
    const bool lz = (wb + n) == 0;         // col -1 lane (kw=0, tt=0)
    const bool rz = (wb + n) == 79;        // col 128 lane (kw=2, tt=3)
    const bf16x8 zfrag = 0;

    #pragma unroll
    for (int kh = 0; kh < 3; ++kh) {
        const int row = (wv >> 1) + kh;    // LDS row 0..3
        #pragma unroll
        for (int kw = 0; kw < 3; ++kw) {
            const int kk = kh * 3 + kw;
            #pragma unroll
            for (int ch = 0; ch < 2; ++ch) {
                bf16x8 a[4], bb[4];
                #pragma unroll
                for (int i = 0; i < 4; ++i)
                    a[i] = __builtin_bit_cast(bf16x8,
                        Wl[((kk * 2 + ch) * 4 + i) * 64 + lane]);
                #pragma unroll
                for (int tt = 0; tt < 4; ++tt) {
                    int c   = wb + tt * 16 + n + kw - 1;    // -1..128
                    int cc  = min(max(c, 0), 127);
                    int idx = (row * 128 + cc) * 8 + ((ch * 4 + q + cc) & 7);
                    bf16x8 v = __builtin_bit_cast(bf16x8, Xl[idx]);
                    if (kw == 0 && tt == 0) v = lz ? zfrag : v;
                    if (kw == 2 && tt == 3) v = rz ? zfrag : v;
                    bb[tt] = v;
                }
                #pragma unroll
                for (int i = 0; i < 4; ++i)
                    #pragma unroll
                    for (int tt = 0; tt < 4; ++tt)
                        acc[i][tt] = __builtin_amdgcn_mfma_f32_16x16x32_bf16(
                            a[i], bb[tt], acc[i][tt], 0, 0, 0);
            }
        }
    }

    // ---- epilogue: oc = i*16 + q*4 + r, w = wb + tt*16 + n, crop mask ----
    const int  h  = h0 + (wv >> 1);
    const bool hz = (h >= 44 && h < 84);
    #pragma unroll
    for (int i = 0; i < 4; ++i) {
        #pragma unroll
        for (int tt = 0; tt < 4; ++tt) {
            const int  w0 = wb + tt * 16 + n;
            const bool zz = hz && (w0 >= 44 && w0 < 84);
            #pragma unroll
            for (int r = 0; r < 4; ++r) {
                const int oc = i * 16 + q * 4 + r;
                out[(((size_t)b * C_ + oc) * H_ + h) * W_ + w0] =
                    zz ? 0.f : acc[i][tt][r];
            }
        }
    }
}

extern "C" void kernel_launch(void* const* d_in, const int* in_sizes, int n_in,
                              void* d_out, int out_size, void* d_ws, size_t ws_size,
                              hipStream_t stream) {
    const float* x   = (const float*)d_in[0];
    const float* wgt = (const float*)d_in[1];
    float* out       = (float*)d_out;
    (void)d_ws; (void)ws_size;   // no workspace needed — single fused kernel
    conv_fused<<<dim3(1024), dim3(256), 0, stream>>>(x, wgt, out);
}

// Round 2
// 132.503 us; speedup vs baseline: 1.0626x; 1.0626x over previous
//
#include <hip/hip_runtime.h>
#include <stdint.h>

// CropConv implicit GEMM (bf16 MFMA, fp32 accum).
//   M=64 (oc), K=576 (ic*3*3), N=262144 (b*h*w)
// v2: occupancy fix.
//   - weights: tiny pre-pass -> bf16 workspace [kk][ch][i][lane] (72 KiB).
//     A-fragment load = lane-consecutive uint4 -> coalesced 1KB/wave, L1/L2-hot.
//   - main kernel LDS = input tile ONLY (64 KiB) -> 2 blocks/CU, 2 waves/SIMD
//     (was 136 KiB -> 1 block/CU -> 1 wave/SIMD, fully latency-exposed).
//   - input staging: gather-transpose, one ds_write_b128 per (r,j) with the
//     XOR-rotate slot swizzle (consecutive-c lanes cycle all 8 bank groups ->
//     conflict-free; replaces 128 scattered ds_write_b16/thread, 7.25M conflicts).
//   - K-loop / edge masks / epilogue carried over from the verified kernel.
// Fallback: if ws_size < 73728, launch the previous fully-fused kernel.

#define B_ 16
#define C_ 64
#define H_ 128
#define W_ 128

#define XLDS_U4 4096   // 4*128*8 uint4 = 64 KiB input tile

typedef float f32x4 __attribute__((ext_vector_type(4)));
typedef short bf16x8 __attribute__((ext_vector_type(8)));

__device__ inline unsigned short f2bf(float f) {
    union { float f; uint32_t u; } v; v.f = f;
    uint32_t u = v.u + 0x7FFF + ((v.u >> 16) & 1);   // RNE
    return (unsigned short)(u >> 16);
}

// ---- pre-pass: weights [oc][ic][3][3] fp32 -> bf16 [kk][ch][i][lane][e] ----
// element L = (((kk*2+ch)*4 + i)*64 + lane)*8 + e  holds
//   wgt[oc = i*16 + (lane&15)][ic = ch*32 + (lane>>4)*8 + e][kk]
__global__ __launch_bounds__(256) void xform_weight(
    const float* __restrict__ wgt, uint16_t* __restrict__ Wb)
{
    int L = blockIdx.x * 256 + threadIdx.x;       // < 36864
    int e    = L & 7;
    int lane = (L >> 3) & 63;
    int i    = (L >> 9) & 3;
    int ch   = (L >> 11) & 1;
    int kk   = L >> 12;
    int oc   = i * 16 + (lane & 15);
    int ic   = ch * 32 + (lane >> 4) * 8 + e;
    Wb[L] = f2bf(wgt[((size_t)oc * 64 + ic) * 9 + kk]);
}

// ---- main: input-only LDS, weights from global (coalesced, L1-hot) ----
// grid 1024, block 256 = 4 waves; wave = (h = h0 + (wv>>1), w-half (wv&1)*64).
// LDS tile: [r:4][c:128][slot:8] uint4, slot = (j + c) & 7, j = ic>>3.
__global__ __launch_bounds__(256, 2) void conv_main(
    const uint4* __restrict__ Wq,    // [9][2][4][64] uint4 bf16
    const float* __restrict__ x,     // [16][64][128][128] fp32
    float* __restrict__ out)         // [16][64][128][128] fp32
{
    __shared__ uint4 lds[XLDS_U4];   // 64 KiB

    const int t    = threadIdx.x;
    const int lane = t & 63;
    const int wv   = t >> 6;
    const int n    = lane & 15;
    const int q    = lane >> 4;

    // XCD-contiguous remap (1024 = 8 * 128, bijective)
    const int d    = blockIdx.x;
    const int orig = (d & 7) * 128 + (d >> 3);
    const int b    = orig >> 6;
    const int h0   = (orig & 63) * 2;

    // ---- stage input: gather-transpose NCHW fp32 -> swizzled bf16 tile ----
    // thread: c = t&127 (one column), j-half = t>>7 (slots 0-3 or 4-7).
    {
        const int c     = t & 127;
        const int jbase = (t >> 7) * 4;
        #pragma unroll
        for (int r = 0; r < 4; ++r) {
            const int h = h0 - 1 + r;                 // -1..128
            if (h < 0 || h >= H_) {                   // halo row: zero
                uint4 z; z.x = z.y = z.z = z.w = 0;
                #pragma unroll
                for (int jj = 0; jj < 4; ++jj)
                    lds[r * 1024 + c * 8 + ((jbase + jj + c) & 7)] = z;
            } else {
                const float* src = x + (((size_t)b * C_) * H_ + h) * W_ + c;
                #pragma unroll
                for (int jj = 0; jj < 4; ++jj) {
                    const int j = jbase + jj;         // ic octet
                    uint32_t u[4];
                    #pragma unroll
                    for (int p = 0; p < 4; ++p) {
                        float v0 = src[(size_t)(j * 8 + 2 * p)     * (H_ * W_)];
                        float v1 = src[(size_t)(j * 8 + 2 * p + 1) * (H_ * W_)];
                        u[p] = (uint32_t)f2bf(v0) | ((uint32_t)f2bf(v1) << 16);
                    }
                    lds[r * 1024 + c * 8 + ((j + c) & 7)] =
                        *(const uint4*)u;
                }
            }
        }
    }
    __syncthreads();

    // ---- K-loop: 18 steps (3 kh x 3 kw x 2 ch), 4x4 MFMA tiles per wave ----
    f32x4 acc[4][4];
    #pragma unroll
    for (int i = 0; i < 4; ++i)
        #pragma unroll
        for (int tt = 0; tt < 4; ++tt)
            acc[i][tt] = (f32x4){0.f, 0.f, 0.f, 0.f};

    const int wb = (wv & 1) * 64;
    const bool lz = (wb + n) == 0;        // col -1 lane (kw=0, tt=0)
    const bool rz = (wb + n) == 79;       // col 128 lane (kw=2, tt=3)
    const bf16x8 zfrag = 0;

    #pragma unroll
    for (int kh = 0; kh < 3; ++kh) {
        const int row = (wv >> 1) + kh;   // LDS row 0..3
        #pragma unroll
        for (int kw = 0; kw < 3; ++kw) {
            const int kk = kh * 3 + kw;
            #pragma unroll
            for (int ch = 0; ch < 2; ++ch) {
                bf16x8 a[4], bb[4];
                #pragma unroll
                for (int i = 0; i < 4; ++i)
                    a[i] = __builtin_bit_cast(bf16x8,
                        Wq[((kk * 2 + ch) * 4 + i) * 64 + lane]);
                #pragma unroll
                for (int tt = 0; tt < 4; ++tt) {
                    int c   = wb + tt * 16 + n + kw - 1;    // -1..128
                    int cc  = min(max(c, 0), 127);
                    int idx = (row * 128 + cc) * 8 + ((ch * 4 + q + cc) & 7);
                    bf16x8 v = __builtin_bit_cast(bf16x8, lds[idx]);
                    if (kw == 0 && tt == 0) v = lz ? zfrag : v;
                    if (kw == 2 && tt == 3) v = rz ? zfrag : v;
                    bb[tt] = v;
                }
                #pragma unroll
                for (int i = 0; i < 4; ++i)
                    #pragma unroll
                    for (int tt = 0; tt < 4; ++tt)
                        acc[i][tt] = __builtin_amdgcn_mfma_f32_16x16x32_bf16(
                            a[i], bb[tt], acc[i][tt], 0, 0, 0);
            }
        }
    }

    // ---- epilogue: oc = i*16 + q*4 + r, w = wb + tt*16 + n, crop mask ----
    const int  h  = h0 + (wv >> 1);
    const bool hz = (h >= 44 && h < 84);
    #pragma unroll
    for (int i = 0; i < 4; ++i) {
        #pragma unroll
        for (int tt = 0; tt < 4; ++tt) {
            const int  w0 = wb + tt * 16 + n;
            const bool zz = hz && (w0 >= 44 && w0 < 84);
            #pragma unroll
            for (int r = 0; r < 4; ++r) {
                const int oc = i * 16 + q * 4 + r;
                out[(((size_t)b * C_ + oc) * H_ + h) * W_ + w0] =
                    zz ? 0.f : acc[i][tt][r];
            }
        }
    }
}

// ================= fallback: fully-fused single kernel (v1, 88.5 us) ========
#define WLDS_U4 4608   // 9*2*4*64 uint4 = 72 KiB weights

__global__ __launch_bounds__(256, 1) void conv_fused(
    const float* __restrict__ x,
    const float* __restrict__ wgt,
    float* __restrict__ out)
{
    __shared__ uint4 lds[WLDS_U4 + XLDS_U4];          // 136 KiB
    uint16_t* lds16 = (uint16_t*)lds;

    const int t    = threadIdx.x;
    const int lane = t & 63;
    const int wv   = t >> 6;
    const int n    = lane & 15;
    const int q    = lane >> 4;

    const int d    = blockIdx.x;
    const int orig = (d & 7) * 128 + (d >> 3);
    const int b    = orig >> 6;
    const int h0   = (orig & 63) * 2;

    #pragma unroll
    for (int p = 0; p < 2; ++p) {
        const int a_  = t + 256 * p;
        const int oc  = a_ >> 3;
        const int oct = a_ & 7;
        const float* src = wgt + (size_t)oc * 576 + (size_t)oct * 72;
        f32x4 w4[18];
        #pragma unroll
        for (int j = 0; j < 18; ++j) w4[j] = ((const f32x4*)src)[j];
        const int ch = oct >> 2, qq = oct & 3;
        const int ii = oc >> 4,  nn = oc & 15;
        #pragma unroll
        for (int kk = 0; kk < 9; ++kk) {
            #define WELEM(e) ((uint32_t)f2bf(w4[((e)*9 + kk) >> 2][((e)*9 + kk) & 3]))
            uint4 val;
            val.x = WELEM(0) | (WELEM(1) << 16);
            val.y = WELEM(2) | (WELEM(3) << 16);
            val.z = WELEM(4) | (WELEM(5) << 16);
            val.w = WELEM(6) | (WELEM(7) << 16);
            #undef WELEM
            lds[((kk * 2 + ch) * 4 + ii) * 64 + qq * 16 + nn] = val;
        }
    }

    {
        const int ic    = t >> 2;
        const int w0    = (t & 3) * 32;
        const int jslot = ic >> 3;
        const int esub  = ic & 7;
        #pragma unroll
        for (int r = 0; r < 4; ++r) {
            const int h = h0 - 1 + r;
            if (h < 0 || h >= H_) {
                uint4 z; z.x = z.y = z.z = z.w = 0;
                #pragma unroll
                for (int k = 0; k < 4; ++k)
                    lds[WLDS_U4 + r * 1024 + k * 256 + t] = z;
            } else {
                const float* src =
                    x + (((size_t)(b * C_ + ic)) * H_ + h) * W_ + w0;
                f32x4 v4[8];
                #pragma unroll
                for (int j = 0; j < 8; ++j) v4[j] = ((const f32x4*)src)[j];
                #pragma unroll
                for (int k = 0; k < 32; ++k) {
                    const int c    = w0 + k;
                    const int slot = (jslot + c) & 7;
                    lds16[WLDS_U4 * 8 + ((r * 128 + c) * 8 + slot) * 8 + esub] =
                        f2bf(v4[k >> 2][k & 3]);
                }
            }
        }
    }
    __syncthreads();

    f32x4 acc[4][4];
    #pragma unroll
    for (int i = 0; i < 4; ++i)
        #pragma unroll
        for (int tt = 0; tt < 4; ++tt)
            acc[i][tt] = (f32x4){0.f, 0.f, 0.f, 0.f};

    const int wb = (wv & 1) * 64;
    const uint4* Wl = lds;
    const uint4* Xl = lds + WLDS_U4;
    const bool lz = (wb + n) == 0;
    const bool rz = (wb + n) == 79;
    const bf16x8 zfrag = 0;

    #pragma unroll
    for (int kh = 0; kh < 3; ++kh) {
        const int row = (wv >> 1) + kh;
        #pragma unroll
        for (int kw = 0; kw < 3; ++kw) {
            const int kk = kh * 3 + kw;
            #pragma unroll
            for (int ch = 0; ch < 2; ++ch) {
                bf16x8 a[4], bb[4];
                #pragma unroll
                for (int i = 0; i < 4; ++i)
                    a[i] = __builtin_bit_cast(bf16x8,
                        Wl[((kk * 2 + ch) * 4 + i) * 64 + lane]);
                #pragma unroll
                for (int tt = 0; tt < 4; ++tt) {
                    int c   = wb + tt * 16 + n + kw - 1;
                    int cc  = min(max(c, 0), 127);
                    int idx = (row * 128 + cc) * 8 + ((ch * 4 + q + cc) & 7);
                    bf16x8 v = __builtin_bit_cast(bf16x8, Xl[idx]);
                    if (kw == 0 && tt == 0) v = lz ? zfrag : v;
                    if (kw == 2 && tt == 3) v = rz ? zfrag : v;
                    bb[tt] = v;
                }
                #pragma unroll
                for (int i = 0; i < 4; ++i)
                    #pragma unroll
                    for (int tt = 0; tt < 4; ++tt)
                        acc[i][tt] = __builtin_amdgcn_mfma_f32_16x16x32_bf16(
                            a[i], bb[tt], acc[i][tt], 0, 0, 0);
            }
        }
    }

    const int  h  = h0 + (wv >> 1);
    const bool hz = (h >= 44 && h < 84);
    #pragma unroll
    for (int i = 0; i < 4; ++i) {
        #pragma unroll
        for (int tt = 0; tt < 4; ++tt) {
            const int  w0 = wb + tt * 16 + n;
            const bool zz = hz && (w0 >= 44 && w0 < 84);
            #pragma unroll
            for (int r = 0; r < 4; ++r) {
                const int oc = i * 16 + q * 4 + r;
                out[(((size_t)b * C_ + oc) * H_ + h) * W_ + w0] =
                    zz ? 0.f : acc[i][tt][r];
            }
        }
    }
}

extern "C" void kernel_launch(void* const* d_in, const int* in_sizes, int n_in,
                              void* d_out, int out_size, void* d_ws, size_t ws_size,
                              hipStream_t stream) {
    const float* x   = (const float*)d_in[0];
    const float* wgt = (const float*)d_in[1];
    float* out       = (float*)d_out;

    const size_t W_BYTES = 9 * 2 * 4 * 64 * 16;   // 73,728
    if (ws_size >= W_BYTES) {
        uint16_t* Wb = (uint16_t*)d_ws;
        xform_weight<<<dim3(144), dim3(256), 0, stream>>>(wgt, Wb);
        conv_main<<<dim3(1024), dim3(256), 0, stream>>>(
            (const uint4*)Wb, x, out);
    } else {
        conv_fused<<<dim3(1024), dim3(256), 0, stream>>>(x, wgt, out);
    }
}

// Round 3
// 130.568 us; speedup vs baseline: 1.0784x; 1.0148x over previous
//
#include <hip/hip_runtime.h>
#include <stdint.h>

// CropConv implicit GEMM (bf16 MFMA, fp32 accum).
//   M=64 (oc), K=576 (ic*3*3), N=262144 (b*h*w)
// v3: occupancy push. Block re-tiled 2hx128w -> 4hx64w:
//   - LDS tile 6 rows x 66 cols (w-halo IN tile) x 64 ic bf16 = 49.5 KiB
//     -> 3 blocks/CU = 3 waves/SIMD (was 64 KiB -> 2/SIMD, Occupancy 17.7%).
//   - wave = 2 h-rows x 32 w -> still 4x4 fragments = 16 MFMA per A-load group
//     (A L2-traffic unchanged); row redundancy 2.0x -> 1.5x.
//   - w-halo in LDS kills the lz/rz edge masks in the K-loop.
//   - swizzle slot = (j + c) & 7 unchanged (row stride 528 = 0 mod 8 -> same
//     bank-group pattern; v2 measured 0 conflicts).
// Weights: tiny pre-pass -> bf16 workspace [kk][ch][i][lane] (72 KiB), A-loads
// lane-consecutive uint4 -> coalesced, L2-hot.
// Fallback: if ws_size < 73728, launch the v1 fully-fused kernel.

#define B_ 16
#define C_ 64
#define H_ 128
#define W_ 128

#define TROWS 6
#define TCOLS 66
#define XLDS_U4 (TROWS * TCOLS * 8)   // 3168 uint4 = 49.5 KiB

typedef float f32x4 __attribute__((ext_vector_type(4)));
typedef short bf16x8 __attribute__((ext_vector_type(8)));

__device__ inline unsigned short f2bf(float f) {
    union { float f; uint32_t u; } v; v.f = f;
    uint32_t u = v.u + 0x7FFF + ((v.u >> 16) & 1);   // RNE
    return (unsigned short)(u >> 16);
}

// ---- pre-pass: weights [oc][ic][3][3] fp32 -> bf16 [kk][ch][i][lane][e] ----
// element L = (((kk*2+ch)*4 + i)*64 + lane)*8 + e  holds
//   wgt[oc = i*16 + (lane&15)][ic = ch*32 + (lane>>4)*8 + e][kk]
__global__ __launch_bounds__(256) void xform_weight(
    const float* __restrict__ wgt, uint16_t* __restrict__ Wb)
{
    int L = blockIdx.x * 256 + threadIdx.x;       // < 36864
    int e    = L & 7;
    int lane = (L >> 3) & 63;
    int i    = (L >> 9) & 3;
    int ch   = (L >> 11) & 1;
    int kk   = L >> 12;
    int oc   = i * 16 + (lane & 15);
    int ic   = ch * 32 + (lane >> 4) * 8 + e;
    Wb[L] = f2bf(wgt[((size_t)oc * 64 + ic) * 9 + kk]);
}

// ---- main: 4h x 64w block, input-only LDS, weights from global ----
// grid 1024 = 16 b x 32 htiles x 2 wsides; block 256 = 4 waves;
// wave wv = (h rows hbase..hbase+1, w-quarter (wv&1)*32), hbase = (wv>>1)*2.
// LDS tile: [r:6][c:66][slot:8] uint4, slot = (j + c) & 7, j = ic>>3.
// tile col c holds global w = wside*64 + c - 1  (halo cols 0 and 65 zeroed/real).
__global__ __launch_bounds__(256, 3) void conv_main(
    const uint4* __restrict__ Wq,    // [9][2][4][64] uint4 bf16
    const float* __restrict__ x,     // [16][64][128][128] fp32
    float* __restrict__ out)         // [16][64][128][128] fp32
{
    __shared__ uint4 lds[XLDS_U4];   // 49.5 KiB

    const int t    = threadIdx.x;
    const int lane = t & 63;
    const int wv   = t >> 6;
    const int n    = lane & 15;
    const int q    = lane >> 4;

    // XCD-contiguous remap (1024 = 8 * 128, bijective): each XCD gets 2 batches
    const int d    = blockIdx.x;
    const int orig = (d & 7) * 128 + (d >> 3);
    const int wsd  = orig & 1;                    // w side: 0 -> w 0..63, 1 -> 64..127
    const int ht   = (orig >> 1) & 31;
    const int b    = orig >> 6;
    const int h0   = ht * 4;

    // ---- stage input: gather-transpose NCHW fp32 -> swizzled bf16 tile ----
    // main: thread = (col 1..64, octet-half, row-triple); 96 scalar loads each,
    // lanes at consecutive cols -> fully coalesced 256B/instr.
    {
        const int cc_   = (t & 63) + 1;           // tile col 1..64
        const int jh    = (t >> 6) & 1;           // octets 0-3 or 4-7
        const int rtri  = (t >> 7) * 3;           // rows 0..2 or 3..5
        const int wglob = wsd * 64 + (t & 63);    // 0..127, always valid
        #pragma unroll
        for (int rr = 0; rr < 3; ++rr) {
            const int r = rtri + rr;
            const int h = h0 - 1 + r;             // -1..128
            if (h < 0 || h >= H_) {               // halo row: zero
                uint4 z; z.x = z.y = z.z = z.w = 0;
                #pragma unroll
                for (int jj = 0; jj < 4; ++jj)
                    lds[(r * TCOLS + cc_) * 8 + ((jh * 4 + jj + cc_) & 7)] = z;
            } else {
                const float* src = x + (((size_t)b * C_) * H_ + h) * W_ + wglob;
                #pragma unroll
                for (int jj = 0; jj < 4; ++jj) {
                    const int j = jh * 4 + jj;    // ic octet
                    uint32_t u[4];
                    #pragma unroll
                    for (int p = 0; p < 4; ++p) {
                        float v0 = src[(size_t)(j * 8 + 2 * p)     * (H_ * W_)];
                        float v1 = src[(size_t)(j * 8 + 2 * p + 1) * (H_ * W_)];
                        u[p] = (uint32_t)f2bf(v0) | ((uint32_t)f2bf(v1) << 16);
                    }
                    lds[(r * TCOLS + cc_) * 8 + ((j + cc_) & 7)] = *(const uint4*)u;
                }
            }
        }
        // tail: halo cols 0 and 65 (96 uint4), wave 0+ divergent but tiny
        if (t < 96) {
            const int j  = t & 7;
            const int r  = (t >> 3) % 6;
            const int ce = (t >= 48) ? (TCOLS - 1) : 0;
            const int h  = h0 - 1 + r;
            const int wg = wsd * 64 + ce - 1;     // -1 | 63 | 64 | 128
            uint4 val; val.x = val.y = val.z = val.w = 0;
            if (h >= 0 && h < H_ && wg >= 0 && wg < W_) {
                const float* src = x + (((size_t)b * C_) * H_ + h) * W_ + wg;
                uint32_t u[4];
                #pragma unroll
                for (int p = 0; p < 4; ++p) {
                    float v0 = src[(size_t)(j * 8 + 2 * p)     * (H_ * W_)];
                    float v1 = src[(size_t)(j * 8 + 2 * p + 1) * (H_ * W_)];
                    u[p] = (uint32_t)f2bf(v0) | ((uint32_t)f2bf(v1) << 16);
                }
                val = *(const uint4*)u;
            }
            lds[(r * TCOLS + ce) * 8 + ((j + ce) & 7)] = val;
        }
    }
    __syncthreads();

    // ---- K-loop: 18 steps (3 kh x 3 kw x 2 ch), 4x4 MFMA tiles per wave ----
    f32x4 acc[4][4];
    #pragma unroll
    for (int i = 0; i < 4; ++i)
        #pragma unroll
        for (int f = 0; f < 4; ++f)
            acc[i][f] = (f32x4){0.f, 0.f, 0.f, 0.f};

    const int wbh   = (wv & 1) * 32;      // w-quarter within 64-col window
    const int hbase = (wv >> 1) * 2;      // output rows hbase, hbase+1

    #pragma unroll
    for (int kh = 0; kh < 3; ++kh) {
        #pragma unroll
        for (int kw = 0; kw < 3; ++kw) {
            const int kk = kh * 3 + kw;
            #pragma unroll
            for (int ch = 0; ch < 2; ++ch) {
                bf16x8 a[4], bb[4];
                #pragma unroll
                for (int i = 0; i < 4; ++i)
                    a[i] = __builtin_bit_cast(bf16x8,
                        Wq[((kk * 2 + ch) * 4 + i) * 64 + lane]);
                #pragma unroll
                for (int f = 0; f < 4; ++f) {
                    const int hh  = f >> 1, tt = f & 1;
                    const int row = hbase + hh + kh;          // 0..5
                    const int ct  = wbh + tt * 16 + n + kw;   // 0..65
                    const int idx = (row * TCOLS + ct) * 8 + ((ch * 4 + q + ct) & 7);
                    bb[f] = __builtin_bit_cast(bf16x8, lds[idx]);
                }
                #pragma unroll
                for (int i = 0; i < 4; ++i)
                    #pragma unroll
                    for (int f = 0; f < 4; ++f)
                        acc[i][f] = __builtin_amdgcn_mfma_f32_16x16x32_bf16(
                            a[i], bb[f], acc[i][f], 0, 0, 0);
            }
        }
    }

    // ---- epilogue: oc = i*16 + q*4 + r, crop mask ----
    #pragma unroll
    for (int f = 0; f < 4; ++f) {
        const int hh = f >> 1, tt = f & 1;
        const int h  = h0 + hbase + hh;
        const int w0 = wsd * 64 + wbh + tt * 16 + n;
        const bool zz = (h >= 44 && h < 84) && (w0 >= 44 && w0 < 84);
        #pragma unroll
        for (int i = 0; i < 4; ++i) {
            #pragma unroll
            for (int r = 0; r < 4; ++r) {
                const int oc = i * 16 + q * 4 + r;
                out[(((size_t)b * C_ + oc) * H_ + h) * W_ + w0] =
                    zz ? 0.f : acc[i][f][r];
            }
        }
    }
}

// ================= fallback: fully-fused single kernel (v1, 88.5 us) ========
#define WLDS_U4 4608   // 9*2*4*64 uint4 = 72 KiB weights
#define FXLDS_U4 4096  // 4*128*8 uint4 = 64 KiB input tile

__global__ __launch_bounds__(256, 1) void conv_fused(
    const float* __restrict__ x,
    const float* __restrict__ wgt,
    float* __restrict__ out)
{
    __shared__ uint4 lds[WLDS_U4 + FXLDS_U4];          // 136 KiB
    uint16_t* lds16 = (uint16_t*)lds;

    const int t    = threadIdx.x;
    const int lane = t & 63;
    const int wv   = t >> 6;
    const int n    = lane & 15;
    const int q    = lane >> 4;

    const int d    = blockIdx.x;
    const int orig = (d & 7) * 128 + (d >> 3);
    const int b    = orig >> 6;
    const int h0   = (orig & 63) * 2;

    #pragma unroll
    for (int p = 0; p < 2; ++p) {
        const int a_  = t + 256 * p;
        const int oc  = a_ >> 3;
        const int oct = a_ & 7;
        const float* src = wgt + (size_t)oc * 576 + (size_t)oct * 72;
        f32x4 w4[18];
        #pragma unroll
        for (int j = 0; j < 18; ++j) w4[j] = ((const f32x4*)src)[j];
        const int ch = oct >> 2, qq = oct & 3;
        const int ii = oc >> 4,  nn = oc & 15;
        #pragma unroll
        for (int kk = 0; kk < 9; ++kk) {
            #define WELEM(e) ((uint32_t)f2bf(w4[((e)*9 + kk) >> 2][((e)*9 + kk) & 3]))
            uint4 val;
            val.x = WELEM(0) | (WELEM(1) << 16);
            val.y = WELEM(2) | (WELEM(3) << 16);
            val.z = WELEM(4) | (WELEM(5) << 16);
            val.w = WELEM(6) | (WELEM(7) << 16);
            #undef WELEM
            lds[((kk * 2 + ch) * 4 + ii) * 64 + qq * 16 + nn] = val;
        }
    }

    {
        const int ic    = t >> 2;
        const int w0    = (t & 3) * 32;
        const int jslot = ic >> 3;
        const int esub  = ic & 7;
        #pragma unroll
        for (int r = 0; r < 4; ++r) {
            const int h = h0 - 1 + r;
            if (h < 0 || h >= H_) {
                uint4 z; z.x = z.y = z.z = z.w = 0;
                #pragma unroll
                for (int k = 0; k < 4; ++k)
                    lds[WLDS_U4 + r * 1024 + k * 256 + t] = z;
            } else {
                const float* src =
                    x + (((size_t)(b * C_ + ic)) * H_ + h) * W_ + w0;
                f32x4 v4[8];
                #pragma unroll
                for (int j = 0; j < 8; ++j) v4[j] = ((const f32x4*)src)[j];
                #pragma unroll
                for (int k = 0; k < 32; ++k) {
                    const int c    = w0 + k;
                    const int slot = (jslot + c) & 7;
                    lds16[WLDS_U4 * 8 + ((r * 128 + c) * 8 + slot) * 8 + esub] =
                        f2bf(v4[k >> 2][k & 3]);
                }
            }
        }
    }
    __syncthreads();

    f32x4 acc[4][4];
    #pragma unroll
    for (int i = 0; i < 4; ++i)
        #pragma unroll
        for (int tt = 0; tt < 4; ++tt)
            acc[i][tt] = (f32x4){0.f, 0.f, 0.f, 0.f};

    const int wb = (wv & 1) * 64;
    const uint4* Wl = lds;
    const uint4* Xl = lds + WLDS_U4;
    const bool lz = (wb + n) == 0;
    const bool rz = (wb + n) == 79;
    const bf16x8 zfrag = 0;

    #pragma unroll
    for (int kh = 0; kh < 3; ++kh) {
        const int row = (wv >> 1) + kh;
        #pragma unroll
        for (int kw = 0; kw < 3; ++kw) {
            const int kk = kh * 3 + kw;
            #pragma unroll
            for (int ch = 0; ch < 2; ++ch) {
                bf16x8 a[4], bb[4];
                #pragma unroll
                for (int i = 0; i < 4; ++i)
                    a[i] = __builtin_bit_cast(bf16x8,
                        Wl[((kk * 2 + ch) * 4 + i) * 64 + lane]);
                #pragma unroll
                for (int tt = 0; tt < 4; ++tt) {
                    int c   = wb + tt * 16 + n + kw - 1;
                    int cc  = min(max(c, 0), 127);
                    int idx = (row * 128 + cc) * 8 + ((ch * 4 + q + cc) & 7);
                    bf16x8 v = __builtin_bit_cast(bf16x8, Xl[idx]);
                    if (kw == 0 && tt == 0) v = lz ? zfrag : v;
                    if (kw == 2 && tt == 3) v = rz ? zfrag : v;
                    bb[tt] = v;
                }
                #pragma unroll
                for (int i = 0; i < 4; ++i)
                    #pragma unroll
                    for (int tt = 0; tt < 4; ++tt)
                        acc[i][tt] = __builtin_amdgcn_mfma_f32_16x16x32_bf16(
                            a[i], bb[tt], acc[i][tt], 0, 0, 0);
            }
        }
    }

    const int  h  = h0 + (wv >> 1);
    const bool hz = (h >= 44 && h < 84);
    #pragma unroll
    for (int i = 0; i < 4; ++i) {
        #pragma unroll
        for (int tt = 0; tt < 4; ++tt) {
            const int  w0 = wb + tt * 16 + n;
            const bool zz = hz && (w0 >= 44 && w0 < 84);
            #pragma unroll
            for (int r = 0; r < 4; ++r) {
                const int oc = i * 16 + q * 4 + r;
                out[(((size_t)b * C_ + oc) * H_ + h) * W_ + w0] =
                    zz ? 0.f : acc[i][tt][r];
            }
        }
    }
}

extern "C" void kernel_launch(void* const* d_in, const int* in_sizes, int n_in,
                              void* d_out, int out_size, void* d_ws, size_t ws_size,
                              hipStream_t stream) {
    const float* x   = (const float*)d_in[0];
    const float* wgt = (const float*)d_in[1];
    float* out       = (float*)d_out;

    const size_t W_BYTES = 9 * 2 * 4 * 64 * 16;   // 73,728
    if (ws_size >= W_BYTES) {
        uint16_t* Wb = (uint16_t*)d_ws;
        xform_weight<<<dim3(144), dim3(256), 0, stream>>>(wgt, Wb);
        conv_main<<<dim3(1024), dim3(256), 0, stream>>>(
            (const uint4*)Wb, x, out);
    } else {
        conv_fused<<<dim3(1024), dim3(256), 0, stream>>>(x, wgt, out);
    }
}